// Round 3
// baseline (180.197 us; speedup 1.0000x reference)
//
#include <hip/hip_runtime.h>

// IDWT 2D Haar: out[b, 4c+o, 2h+i, 2w+j] = (sum_n x[b, n*C+c, h, w]) * filt[o,i,j]
// x: (B=8, 192, 128, 128) f32; filt: (4,2,2) f32; out: (8, 192, 256, 256) f32.

constexpr int B  = 8;
constexpr int C  = 48;    // groups
constexpr int C4 = 192;   // 4*C
constexpr int H  = 128;
constexpr int W  = 128;
constexpr int HO = 256;
constexpr int WO = 256;
constexpr int W4 = W / 4; // 4 w-positions per thread -> 32 lanes per input row

typedef float floatx4 __attribute__((ext_vector_type(4)));

__global__ __launch_bounds__(256)
void idwt2d_haar_kernel(const float* __restrict__ x,
                        const float* __restrict__ filt,
                        float* __restrict__ out) {
    // linear index over (b, c, h, w4); consecutive lanes -> consecutive w4
    unsigned idx = blockIdx.x * blockDim.x + threadIdx.x;
    const unsigned w4 = idx & (W4 - 1);       // 32 per row
    unsigned t = idx >> 5;
    const unsigned h = t & (H - 1);           // 128
    t >>= 7;
    const unsigned c = t % C;
    const unsigned b = t / C;
    if (b >= B) return;

    constexpr unsigned plane = H * W;         // 16384 elements
    const unsigned xoff = (b * C4 + c) * plane + h * W + w4 * 4;

    // sum over 4 subbands: 16B loads
    const floatx4 v0 = *(const floatx4*)(x + xoff);
    const floatx4 v1 = *(const floatx4*)(x + xoff + C * plane);
    const floatx4 v2 = *(const floatx4*)(x + xoff + 2 * C * plane);
    const floatx4 v3 = *(const floatx4*)(x + xoff + 3 * C * plane);
    const floatx4 s = (v0 + v1) + (v2 + v3);

    // out base: channel 4c, row 2h, col 8*w4 (16B aligned)
    const unsigned obase = ((b * C4 + 4 * c) * HO + 2 * h) * WO + 8 * w4;

    #pragma unroll
    for (int o = 0; o < 4; ++o) {
        #pragma unroll
        for (int i = 0; i < 2; ++i) {
            const float f0 = filt[o * 4 + i * 2 + 0];
            const float f1 = filt[o * 4 + i * 2 + 1];
            float* op = out + obase + (unsigned)(o * HO + i) * WO;
            floatx4 a;
            a.x = s.x * f0; a.y = s.x * f1; a.z = s.y * f0; a.w = s.y * f1;
            floatx4 b4;
            b4.x = s.z * f0; b4.y = s.z * f1; b4.z = s.w * f0; b4.w = s.w * f1;
            __builtin_nontemporal_store(a,  (floatx4*)(op));
            __builtin_nontemporal_store(b4, (floatx4*)(op + 4));
        }
    }
}

extern "C" void kernel_launch(void* const* d_in, const int* in_sizes, int n_in,
                              void* d_out, int out_size, void* d_ws, size_t ws_size,
                              hipStream_t stream) {
    const float* x    = (const float*)d_in[0];
    const float* filt = (const float*)d_in[1];
    float* out = (float*)d_out;

    const long long total = (long long)B * C * H * W4; // 1,572,864 threads
    const int block = 256;
    const int grid = (int)((total + block - 1) / block); // 6144
    idwt2d_haar_kernel<<<grid, block, 0, stream>>>(x, filt, out);
}

// Round 4
// 75.499 us; speedup vs baseline: 2.3867x; 2.3867x over previous
//
#include <hip/hip_runtime.h>

// IDWT 2D Haar: out[b, 4c+o, 2h+i, 2w+j] = (sum_n x[b, n*C+c, h, w]) * filt[o,i,j]
// x: (B=8, 192, 128, 128) f32; filt: (4,2,2) f32; out: (8, 192, 256, 256) f32.
//
// Mapping (R1-proven): thread owns 2 input cols -> 4 output cols. Each store
// is float4 at 16B/lane stride => one wave store = 1KB fully contiguous
// (required for non-temporal stores: no L2 merge of holes).

constexpr int B  = 8;
constexpr int C  = 48;    // groups
constexpr int C4 = 192;   // 4*C
constexpr int H  = 128;
constexpr int W  = 128;
constexpr int HO = 256;
constexpr int WO = 256;
constexpr int W2 = W / 2; // 2 w-positions per thread -> 64 lanes per input row

typedef float floatx2 __attribute__((ext_vector_type(2)));
typedef float floatx4 __attribute__((ext_vector_type(4)));

__global__ __launch_bounds__(256)
void idwt2d_haar_kernel(const float* __restrict__ x,
                        const float* __restrict__ filt,
                        float* __restrict__ out) {
    // linear index over (b, c, h, w2); consecutive lanes -> consecutive w2
    unsigned idx = blockIdx.x * blockDim.x + threadIdx.x;
    const unsigned w2 = idx & (W2 - 1);       // 64 per row
    unsigned t = idx >> 6;
    const unsigned h = t & (H - 1);           // 128
    t >>= 7;
    const unsigned c = t % C;
    const unsigned b = t / C;
    if (b >= B) return;

    constexpr unsigned plane = H * W;         // 16384 elements
    const unsigned xoff = (b * C4 + c) * plane + h * W + w2 * 2;

    // sum over 4 subbands: 8B loads (cache-allocating: keep input L3-resident)
    const floatx2 v0 = *(const floatx2*)(x + xoff);
    const floatx2 v1 = *(const floatx2*)(x + xoff + C * plane);
    const floatx2 v2 = *(const floatx2*)(x + xoff + 2 * C * plane);
    const floatx2 v3 = *(const floatx2*)(x + xoff + 3 * C * plane);
    const floatx2 s = (v0 + v1) + (v2 + v3);

    // out base: channel 4c, row 2h, col 4*w2 (16B aligned)
    const unsigned obase = ((b * C4 + 4 * c) * HO + 2 * h) * WO + 4 * w2;

    #pragma unroll
    for (int o = 0; o < 4; ++o) {
        #pragma unroll
        for (int i = 0; i < 2; ++i) {
            const float f0 = filt[o * 4 + i * 2 + 0];
            const float f1 = filt[o * 4 + i * 2 + 1];
            floatx4 a;
            a.x = s.x * f0; a.y = s.x * f1; a.z = s.y * f0; a.w = s.y * f1;
            __builtin_nontemporal_store(
                a, (floatx4*)(out + obase + (unsigned)(o * HO + i) * WO));
        }
    }
}

extern "C" void kernel_launch(void* const* d_in, const int* in_sizes, int n_in,
                              void* d_out, int out_size, void* d_ws, size_t ws_size,
                              hipStream_t stream) {
    const float* x    = (const float*)d_in[0];
    const float* filt = (const float*)d_in[1];
    float* out = (float*)d_out;

    const long long total = (long long)B * C * H * W2; // 3,145,728 threads
    const int block = 256;
    const int grid = (int)((total + block - 1) / block); // 12288
    idwt2d_haar_kernel<<<grid, block, 0, stream>>>(x, filt, out);
}